// Round 1
// baseline (239.059 us; speedup 1.0000x reference)
//
#include <hip/hip_runtime.h>

// LIF spike scan: x[N, T=32] fp32, scan over contiguous T axis.
//   u = 0.25*u*(1-o_prev) + x_t ;  o = (u > 0.5) ? 1 : 0
// One thread per neuron (row). 0.25*u is exact (pow2), (1-o) in {0,1} exact,
// so result is bit-exact vs numpy fp32 reference regardless of fp-contract.

constexpr int T = 32;
constexpr float TAU = 0.25f;
constexpr float VTH = 0.5f;

__global__ __launch_bounds__(256) void LIFSpike_kernel(
    const float* __restrict__ x, float* __restrict__ out, int n_neurons) {
    int i = blockIdx.x * blockDim.x + threadIdx.x;
    if (i >= n_neurons) return;

    const float4* __restrict__ xp = reinterpret_cast<const float4*>(x) + (size_t)i * (T / 4);
    float4* __restrict__ op = reinterpret_cast<float4*>(out) + (size_t)i * (T / 4);

    // Load entire 128B row (one cache line) with 8 outstanding float4 loads.
    float4 buf[T / 4];
#pragma unroll
    for (int j = 0; j < T / 4; ++j) buf[j] = xp[j];

    float u = 0.0f, o = 0.0f;
#pragma unroll
    for (int j = 0; j < T / 4; ++j) {
        float xs0 = buf[j].x, xs1 = buf[j].y, xs2 = buf[j].z, xs3 = buf[j].w;
        float4 r;

        u = TAU * u * (1.0f - o) + xs0;
        o = (u > VTH) ? 1.0f : 0.0f;
        r.x = o;

        u = TAU * u * (1.0f - o) + xs1;
        o = (u > VTH) ? 1.0f : 0.0f;
        r.y = o;

        u = TAU * u * (1.0f - o) + xs2;
        o = (u > VTH) ? 1.0f : 0.0f;
        r.z = o;

        u = TAU * u * (1.0f - o) + xs3;
        o = (u > VTH) ? 1.0f : 0.0f;
        r.w = o;

        op[j] = r;
    }
}

extern "C" void kernel_launch(void* const* d_in, const int* in_sizes, int n_in,
                              void* d_out, int out_size, void* d_ws, size_t ws_size,
                              hipStream_t stream) {
    const float* x = (const float*)d_in[0];
    float* out = (float*)d_out;
    int n_neurons = in_sizes[0] / T;  // 16*128*512 = 1,048,576
    int block = 256;
    int grid = (n_neurons + block - 1) / block;  // 4096
    LIFSpike_kernel<<<grid, block, 0, stream>>>(x, out, n_neurons);
}

// Round 2
// 229.734 us; speedup vs baseline: 1.0406x; 1.0406x over previous
//
#include <hip/hip_runtime.h>

// LIF spike scan: x[N, T=32] fp32, scan over contiguous T axis.
//   u = 0.25*u*(1-o_prev) + x_t ;  o = (u > 0.5) ? 1 : 0
// 0.25*u exact (pow2), (1-o) in {0,1} exact -> bit-exact vs numpy fp32 ref.
//
// R2: fully-coalesced global accesses via LDS tile transpose.
// Block = 256 threads = 256 neurons x 32 steps = 2048 float4 = 32 KB LDS.
// XOR swizzle (s ^ ((s>>3)&7)) makes both the coalesced phase-1/4 accesses
// and the per-row phase-2 accesses conflict-free on 32 banks.

constexpr int T = 32;
constexpr float TAU = 0.25f;
constexpr float VTH = 0.5f;
constexpr int QUADS_PER_ROW = T / 4;          // 8 float4 per neuron row
constexpr int TILE_F4 = 256 * QUADS_PER_ROW;  // 2048 float4 per block

__device__ __forceinline__ int swz(int s) { return s ^ ((s >> 3) & 7); }

__global__ __launch_bounds__(256) void LIFSpike_kernel(
    const float* __restrict__ x, float* __restrict__ out) {
    __shared__ float4 tile[TILE_F4];  // 32 KB

    const int t = threadIdx.x;
    const size_t base = (size_t)blockIdx.x * TILE_F4;  // in float4 units

    // Phase 1: coalesced global -> LDS (lane-consecutive 16B).
    const float4* __restrict__ xp = reinterpret_cast<const float4*>(x);
#pragma unroll
    for (int k = 0; k < QUADS_PER_ROW; ++k) {
        int s = k * 256 + t;
        tile[swz(s)] = xp[base + s];
    }
    __syncthreads();

    // Phase 2: each thread scans its own 32-step row (thread-private in LDS,
    // so in-place result writeback needs no barrier).
    float u = 0.0f, o = 0.0f;
#pragma unroll
    for (int j = 0; j < QUADS_PER_ROW; ++j) {
        int phys = t * QUADS_PER_ROW + (j ^ (t & 7));
        float4 v = tile[phys];
        float4 r;

        u = TAU * u * (1.0f - o) + v.x;
        o = (u > VTH) ? 1.0f : 0.0f;
        r.x = o;

        u = TAU * u * (1.0f - o) + v.y;
        o = (u > VTH) ? 1.0f : 0.0f;
        r.y = o;

        u = TAU * u * (1.0f - o) + v.z;
        o = (u > VTH) ? 1.0f : 0.0f;
        r.z = o;

        u = TAU * u * (1.0f - o) + v.w;
        o = (u > VTH) ? 1.0f : 0.0f;
        r.w = o;

        tile[phys] = r;
    }
    __syncthreads();

    // Phase 3: coalesced LDS -> global.
    float4* __restrict__ op = reinterpret_cast<float4*>(out);
#pragma unroll
    for (int k = 0; k < QUADS_PER_ROW; ++k) {
        int s = k * 256 + t;
        op[base + s] = tile[swz(s)];
    }
}

extern "C" void kernel_launch(void* const* d_in, const int* in_sizes, int n_in,
                              void* d_out, int out_size, void* d_ws, size_t ws_size,
                              hipStream_t stream) {
    const float* x = (const float*)d_in[0];
    float* out = (float*)d_out;
    int total_f4 = in_sizes[0] / 4;       // 8,388,608
    int grid = total_f4 / TILE_F4;        // 4096 blocks (exact)
    LIFSpike_kernel<<<grid, 256, 0, stream>>>(x, out);
}